// Round 6
// baseline (480.660 us; speedup 1.0000x reference)
//
#include <hip/hip_runtime.h>

// B=4, C=512, H=W=64 -> N=4096 tokens, KEY_DIM=VALUE_DIM=512.
// Pipeline (all matmuls on v_mfma_f32_16x16x32_bf16, fp32 accum):
//   K1 qkv_proj   : Qt (B,N,D) bf16 token-major; K in B-FRAGMENT-TILE layout
//                   Kf[b][kblk(256)][dc(16)][lane(64)][8] (key=kblk*16+(lane&15),
//                   d=dc*32+(lane>>4)*8+j); V in A-fragment-tile Vt (as R5).
//   K2 attn_lsum_p: barrier-free QK^T stream. Q staged once to LDS (A-frag
//                   order, 32KB); K frags direct-global coalesced (1KB/instr),
//                   double-buffered; each K frag feeds 2 q-tiles (32 FLOP/B of
//                   L2). Pexp=exp(S) scatter-stored to Pt (K3 B-frag layout);
//                   l_j via fp32 atomics.
//   K3 attn_pv    : O = V.Pexp^T; all fragment loads 1KB-coalesced; no
//                   LDS/barriers/atomics (unchanged from R5).
//   K4 colsum_k   : scores[i] = sum_q Pexp[q,i]/l[q] (unchanged from R5).
// No max-subtraction in softmax: logits ~ N(0,1), exp() can't overflow.
// ws: Qt/Kf/Vt 50.3 MB + l 64 KB + Pexp 134.2 MB = 184.7 MB.

typedef short bf16x8 __attribute__((ext_vector_type(8)));
typedef float f32x4 __attribute__((ext_vector_type(4)));

#define NTOK 4096
#define DDIM 512
#define NB   4

__device__ __forceinline__ unsigned short f32_bf16(float f) {
  union { float f; unsigned u; } v; v.f = f;
  unsigned r = v.u + 0x7FFFu + ((v.u >> 16) & 1u);  // RNE
  return (unsigned short)(r >> 16);
}

__device__ __forceinline__ float bf16_f32(short s) {
  union { unsigned u; float f; } v;
  v.u = ((unsigned)(unsigned short)s) << 16;
  return v.f;
}

// ---------------------------------------------------------------------------
// K1: QKV projection.  Q[n,d] = sum_c x[c,n] * Wq[d,c]  (x is (C,N) per batch)
// ---------------------------------------------------------------------------
__global__ __launch_bounds__(256, 4) void qkv_proj(
    const float* __restrict__ x,
    const float* __restrict__ Wq,
    const float* __restrict__ Wk,
    const float* __restrict__ Wv,
    unsigned short* __restrict__ Qt,
    unsigned short* __restrict__ Kf,
    unsigned short* __restrict__ Vt)
{
  const int nt0 = blockIdx.x * 64;   // token tile
  const int d0  = blockIdx.y * 64;   // feature tile
  const int b   = blockIdx.z;
  const int tid = threadIdx.x;
  const int wave = tid >> 6;
  const int lane = tid & 63;
  const int l15  = lane & 15;
  const int quad = lane >> 4;

  __shared__ __align__(16) unsigned short Xt[64 * 40];     // [token][c]
  __shared__ __align__(16) unsigned short Wl[3][64 * 40];  // [q/k/v][d][c]

  f32x4 aq[4], ak[4], av[4];
#pragma unroll
  for (int i = 0; i < 4; ++i) {
    aq[i] = (f32x4){0.f,0.f,0.f,0.f};
    ak[i] = (f32x4){0.f,0.f,0.f,0.f};
    av[i] = (f32x4){0.f,0.f,0.f,0.f};
  }

  const float* xb = x + (size_t)b * DDIM * NTOK + nt0;
  const int xn  = tid & 63;
  const int xc8 = tid >> 6;
  const int wc8 = tid & 3;
  const int wdd = tid >> 2;

  for (int cc = 0; cc < DDIM; cc += 32) {
    __syncthreads();
    {
      bf16x8 t;
#pragma unroll
      for (int j = 0; j < 8; ++j)
        t[j] = (short)f32_bf16(xb[(size_t)(cc + xc8 * 8 + j) * NTOK + xn]);
      *(bf16x8*)(&Xt[xn * 40 + xc8 * 8]) = t;
    }
    {
      const float* wsrc[3] = {Wq, Wk, Wv};
#pragma unroll
      for (int m = 0; m < 3; ++m) {
        const float* src = wsrc[m] + (size_t)(d0 + wdd) * DDIM + cc + wc8 * 8;
        bf16x8 t;
#pragma unroll
        for (int j = 0; j < 8; ++j) t[j] = (short)f32_bf16(src[j]);
        *(bf16x8*)(&Wl[m][wdd * 40 + wc8 * 8]) = t;
      }
    }
    __syncthreads();

    bf16x8 xa  = *(const bf16x8*)(&Xt[(wave * 16 + l15) * 40 + quad * 8]);
    bf16x8 wva = *(const bf16x8*)(&Wl[2][(wave * 16 + l15) * 40 + quad * 8]);
#pragma unroll
    for (int nt = 0; nt < 4; ++nt) {
      bf16x8 wqf = *(const bf16x8*)(&Wl[0][(nt * 16 + l15) * 40 + quad * 8]);
      bf16x8 wkf = *(const bf16x8*)(&Wl[1][(nt * 16 + l15) * 40 + quad * 8]);
      bf16x8 xbf = *(const bf16x8*)(&Xt[(nt * 16 + l15) * 40 + quad * 8]);
      aq[nt] = __builtin_amdgcn_mfma_f32_16x16x32_bf16(xa,  wqf, aq[nt], 0, 0, 0);
      ak[nt] = __builtin_amdgcn_mfma_f32_16x16x32_bf16(xa,  wkf, ak[nt], 0, 0, 0);
      av[nt] = __builtin_amdgcn_mfma_f32_16x16x32_bf16(wva, xbf, av[nt], 0, 0, 0);
    }
  }

#pragma unroll
  for (int nt = 0; nt < 4; ++nt) {
#pragma unroll
    for (int r = 0; r < 4; ++r) {
      const int tokq = nt0 + wave * 16 + quad * 4 + r;
      const int dq   = d0 + nt * 16 + l15;
      Qt[((size_t)b * NTOK + tokq) * DDIM + dq] = f32_bf16(aq[nt][r]);
      // K fragment-tile store (B-operand of 16x16x32): key=tokq, d=dq ->
      // kblk=key>>4, dc=d>>5, laneK=((d>>3)&3)*16+(key&15), j=d&7
      {
        const int kblk  = (nt0 >> 4) + wave;
        const int dc    = (d0 >> 5) + (nt >> 1);
        const int laneK = ((nt & 1) * 2 + (l15 >> 3)) * 16 + quad * 4 + r;
        Kf[((size_t)(b * 256 + kblk) * 16 + dc) * 512 + laneK * 8 + (l15 & 7)] =
            f32_bf16(ak[nt][r]);
      }
      // V fragment-tile store: d = d0+wave*16+quad*4+r, i = nt0+nt*16+l15
      const int dblk  = (d0 >> 4) + wave;
      const int ic    = (nt0 >> 5) + (nt >> 1);
      const int laneV = ((nt & 1) * 2 + (l15 >> 3)) * 16 + quad * 4 + r;
      Vt[(size_t)b * DDIM * NTOK +
         ((size_t)(dblk * 128 + ic) * 64 + laneV) * 8 + (l15 & 7)] =
          f32_bf16(av[nt][r]);
    }
  }
}

// ---------------------------------------------------------------------------
#define SCALE 0.044194173824159216f  // 1/sqrt(512)

// ---------------------------------------------------------------------------
// K2: barrier-free QK^T -> Pexp + row-sum atomics.
// Grid (128 qb(32q), 2 kp, NB) = 1024 WGs.  Block: 32 q x 2048 keys.
// Q staged ONCE to LDS in A-frag order (one barrier); K frags streamed from
// global (coalesced 1KB loads, register double-buffer); each K frag feeds the
// 2 q-tiles -> 32 FLOP per L2 byte.
// ---------------------------------------------------------------------------
__global__ __launch_bounds__(256, 3) void attn_lsum_p(
    const unsigned short* __restrict__ Qt,
    const unsigned short* __restrict__ Kf,
    unsigned short* __restrict__ Pt,
    float* __restrict__ lsum_g)
{
  const int qb = blockIdx.x;   // 32-q block
  const int kp = blockIdx.y;   // key half
  const int b  = blockIdx.z;
  const int tid  = threadIdx.x;
  const int wave = tid >> 6;
  const int lane = tid & 63;
  const int l15  = lane & 15;
  const int quad = lane >> 4;
  const int q0   = qb * 32;

  // Qlds[qt(2)][dc(16)][lane(64)][8] — A-frag order, wave reads lane*16B contig.
  __shared__ __align__(16) unsigned short Qlds[2 * 16 * 64 * 8];  // 32 KB

  {
    const int q  = tid >> 3;        // 0..31
    const int dg = tid & 7;
    const unsigned short* src = Qt + ((size_t)b * NTOK + q0 + q) * DDIM;
#pragma unroll
    for (int u = 0; u < 8; ++u) {
      const int d = u * 64 + dg * 8;
      bf16x8 t = *(const bf16x8*)(src + d);
      *(bf16x8*)&Qlds[((((q >> 4) * 16 + (d >> 5)) * 64) +
                       ((d >> 3) & 3) * 16 + (q & 15)) * 8] = t;
    }
  }
  __syncthreads();  // the only barrier

  const unsigned short* kfb = Kf + (size_t)b * NTOK * DDIM;  // frag-tile base
  const int kb0 = kp * 128 + wave * 32;  // this wave's 32 key-blocks (512 keys)
  unsigned short* Pq = Pt + (size_t)b * NTOK * NTOK + (size_t)(q0 >> 6) * 262144;
  const int ntP0 = (q0 >> 4) & 3;        // 0 or 2

  float ls[2][4] = {{0.f,0.f,0.f,0.f},{0.f,0.f,0.f,0.f}};

  bf16x8 kA[8], kB[8];
  {
    const unsigned short* p0 = kfb + (size_t)kb0 * 8192 + lane * 8;
#pragma unroll
    for (int dc = 0; dc < 8; ++dc) kA[dc] = *(const bf16x8*)(p0 + dc * 512);
  }

  for (int kb = 0; kb < 32; ++kb) {
    const int kabs = kb0 + kb;
    const unsigned short* pb = kfb + (size_t)kabs * 8192 + lane * 8;
#pragma unroll
    for (int dc = 0; dc < 8; ++dc) kB[dc] = *(const bf16x8*)(pb + (8 + dc) * 512);

    f32x4 s0 = (f32x4){0.f,0.f,0.f,0.f};
    f32x4 s1 = (f32x4){0.f,0.f,0.f,0.f};
#pragma unroll
    for (int dc = 0; dc < 8; ++dc) {
      bf16x8 qa0 = *(const bf16x8*)&Qlds[(dc * 64 + lane) * 8];
      bf16x8 qa1 = *(const bf16x8*)&Qlds[((16 + dc) * 64 + lane) * 8];
      s0 = __builtin_amdgcn_mfma_f32_16x16x32_bf16(qa0, kA[dc], s0, 0, 0, 0);
      s1 = __builtin_amdgcn_mfma_f32_16x16x32_bf16(qa1, kA[dc], s1, 0, 0, 0);
    }
    if (kb < 31) {  // prefetch next key-block's first d-half
      const unsigned short* pn = kfb + (size_t)(kabs + 1) * 8192 + lane * 8;
#pragma unroll
      for (int dc = 0; dc < 8; ++dc) kA[dc] = *(const bf16x8*)(pn + dc * 512);
    }
#pragma unroll
    for (int dc = 0; dc < 8; ++dc) {
      bf16x8 qa0 = *(const bf16x8*)&Qlds[((8 + dc) * 64 + lane) * 8];
      bf16x8 qa1 = *(const bf16x8*)&Qlds[((24 + dc) * 64 + lane) * 8];
      s0 = __builtin_amdgcn_mfma_f32_16x16x32_bf16(qa0, kB[dc], s0, 0, 0, 0);
      s1 = __builtin_amdgcn_mfma_f32_16x16x32_bf16(qa1, kB[dc], s1, 0, 0, 0);
    }

    // epilogue: C layout col=i=l15 (key = kabs*16+l15), row=q=qt*16+quad*4+r
    const int ic    = kabs >> 1;
    const int lt_hi = ((kabs & 1) * 2 + (l15 >> 3)) * 16;
    const int jj    = l15 & 7;
#pragma unroll
    for (int r = 0; r < 4; ++r) {
      const float e0 = __expf(s0[r] * SCALE);
      const float e1 = __expf(s1[r] * SCALE);
      ls[0][r] += e0;
      ls[1][r] += e1;
      Pq[((size_t)(ic * 4 + ntP0) * 64 + lt_hi + quad * 4 + r) * 8 + jj] = f32_bf16(e0);
      Pq[((size_t)(ic * 4 + ntP0 + 1) * 64 + lt_hi + quad * 4 + r) * 8 + jj] = f32_bf16(e1);
    }
  }

  // reduce over the 16 key-columns (l15) and accumulate l_j
#pragma unroll
  for (int qt = 0; qt < 2; ++qt)
#pragma unroll
    for (int r = 0; r < 4; ++r) {
      float v = ls[qt][r];
      v += __shfl_xor(v, 1);
      v += __shfl_xor(v, 2);
      v += __shfl_xor(v, 4);
      v += __shfl_xor(v, 8);
      if (l15 == 0)
        unsafeAtomicAdd(&lsum_g[(size_t)b * NTOK + q0 + qt * 16 + quad * 4 + r], v);
    }
}

// ---------------------------------------------------------------------------
// K3: O = V.Pexp^T.  Grid (64 q0b, 2 dpart, NB) = 512 WGs (2/CU, 8 waves).
// Wave owns 64 d x 64 q.  Per ic: 8 coalesced 1-KB loads + 16 MFMA.
// No LDS, no barriers, no atomics; plain coalesced epilogue stores.
// ---------------------------------------------------------------------------
__global__ __launch_bounds__(256, 2) void attn_pv(
    const unsigned short* __restrict__ Pt,
    const unsigned short* __restrict__ Vt,
    const float* __restrict__ lsum_g,
    float* __restrict__ out)
{
  const int q0b   = blockIdx.x;
  const int dpart = blockIdx.y;
  const int b     = blockIdx.z;
  const int tid  = threadIdx.x;
  const int wave = tid >> 6;
  const int lane = tid & 63;
  const int l15  = lane & 15;
  const int quad = lane >> 4;

  const int dblk0 = dpart * 16 + wave * 4;  // base 16-d tile index
  const unsigned short* Pq =
      Pt + (size_t)b * NTOK * NTOK + (size_t)q0b * 262144 + lane * 8;
  const unsigned short* Vb =
      Vt + (size_t)b * DDIM * NTOK + lane * 8;

  float rlv[4];
#pragma unroll
  for (int nt = 0; nt < 4; ++nt)
    rlv[nt] = 1.0f / lsum_g[(size_t)b * NTOK + q0b * 64 + nt * 16 + l15];

  f32x4 o[4][4];
#pragma unroll
  for (int i = 0; i < 4; ++i)
#pragma unroll
    for (int j = 0; j < 4; ++j) o[i][j] = (f32x4){0.f,0.f,0.f,0.f};

  bf16x8 pc[4], vc[4], pn[4], vn[4];
#pragma unroll
  for (int nt = 0; nt < 4; ++nt)
    pc[nt] = *(const bf16x8*)(Pq + (size_t)nt * 512);
#pragma unroll
  for (int mt = 0; mt < 4; ++mt)
    vc[mt] = *(const bf16x8*)(Vb + (size_t)(dblk0 + mt) * 65536);

#pragma unroll 2
  for (int ic = 0; ic < 127; ++ic) {
    // prefetch next chunk (fully coalesced 1-KB loads)
#pragma unroll
    for (int nt = 0; nt < 4; ++nt)
      pn[nt] = *(const bf16x8*)(Pq + (size_t)(ic + 1) * 2048 + (size_t)nt * 512);
#pragma unroll
    for (int mt = 0; mt < 4; ++mt)
      vn[mt] = *(const bf16x8*)(Vb + (size_t)(dblk0 + mt) * 65536 + (size_t)(ic + 1) * 512);
#pragma unroll
    for (int mt = 0; mt < 4; ++mt)
#pragma unroll
      for (int nt = 0; nt < 4; ++nt)
        o[mt][nt] = __builtin_amdgcn_mfma_f32_16x16x32_bf16(vc[mt], pc[nt], o[mt][nt], 0, 0, 0);
#pragma unroll
    for (int nt = 0; nt < 4; ++nt) pc[nt] = pn[nt];
#pragma unroll
    for (int mt = 0; mt < 4; ++mt) vc[mt] = vn[mt];
  }
#pragma unroll
  for (int mt = 0; mt < 4; ++mt)
#pragma unroll
    for (int nt = 0; nt < 4; ++nt)
      o[mt][nt] = __builtin_amdgcn_mfma_f32_16x16x32_bf16(vc[mt], pc[nt], o[mt][nt], 0, 0, 0);

  // epilogue: plain stores, 1/l folded in (per output column q).
  float* ob = out + ((size_t)b * DDIM + dpart * 256 + wave * 64) * NTOK + q0b * 64;
#pragma unroll
  for (int mt = 0; mt < 4; ++mt)
#pragma unroll
    for (int nt = 0; nt < 4; ++nt)
#pragma unroll
      for (int r = 0; r < 4; ++r)
        ob[(size_t)(mt * 16 + quad * 4 + r) * NTOK + nt * 16 + l15] =
            o[mt][nt][r] * rlv[nt];
}

// ---------------------------------------------------------------------------
// K4: scores[b][i] = sum_q Pexp[b][q][i] / l[b][q].  Tile-layout streaming.
// Grid (128 ic, NB); block exclusively owns i in [ic*32, +32) -> plain stores.
// ---------------------------------------------------------------------------
__global__ __launch_bounds__(256, 4) void colsum_k(
    const unsigned short* __restrict__ Pt,
    const float* __restrict__ lsum_g,
    float* __restrict__ scores_out)
{
  const int ic = blockIdx.x;
  const int b  = blockIdx.y;
  const int tid = threadIdx.x;
  const int wave = tid >> 6;
  const int lane = tid & 63;
  const int l15  = lane & 15;
  const int quad = lane >> 4;

  __shared__ float red[4][32];

  const unsigned short* Pb = Pt + (size_t)b * NTOK * NTOK + (size_t)ic * 2048 + lane * 8;
  const float* lb = lsum_g + (size_t)b * NTOK;

  float acc[8];
#pragma unroll
  for (int j = 0; j < 8; ++j) acc[j] = 0.f;

  for (int q0b = wave; q0b < 64; q0b += 4) {
    const unsigned short* src = Pb + (size_t)q0b * 262144;
#pragma unroll
    for (int nt = 0; nt < 4; ++nt) {
      const bf16x8 p = *(const bf16x8*)(src + (size_t)nt * 512);
      const float rl = 1.0f / lb[q0b * 64 + nt * 16 + l15];
#pragma unroll
      for (int j = 0; j < 8; ++j) acc[j] = fmaf(bf16_f32(p[j]), rl, acc[j]);
    }
  }
  // reduce over the 16 q-residues (l15) within the wave
#pragma unroll
  for (int j = 0; j < 8; ++j) {
    float v = acc[j];
    v += __shfl_xor(v, 1);
    v += __shfl_xor(v, 2);
    v += __shfl_xor(v, 4);
    v += __shfl_xor(v, 8);
    acc[j] = v;
  }
  if (l15 == 0) {
#pragma unroll
    for (int j = 0; j < 8; ++j) red[wave][quad * 8 + j] = acc[j];
  }
  __syncthreads();
  if (tid < 32)
    scores_out[(size_t)b * NTOK + ic * 32 + tid] =
        red[0][tid] + red[1][tid] + red[2][tid] + red[3][tid];
}

// ---------------------------------------------------------------------------
extern "C" void kernel_launch(void* const* d_in, const int* in_sizes, int n_in,
                              void* d_out, int out_size, void* d_ws, size_t ws_size,
                              hipStream_t stream) {
  const float* x  = (const float*)d_in[0];
  const float* Wk = (const float*)d_in[1];  // dict order: x, Wk, Wq, Wv
  const float* Wq = (const float*)d_in[2];
  const float* Wv = (const float*)d_in[3];

  float* out = (float*)d_out;
  float* scores_out = out + (size_t)NB * DDIM * NTOK;  // tail of d_out

  const size_t mat_elems = (size_t)NB * NTOK * DDIM;   // 8388608
  unsigned short* Qt = (unsigned short*)d_ws;
  unsigned short* Kf = Qt + mat_elems;
  unsigned short* Vt = Kf + mat_elems;
  float* lbuf = (float*)(Vt + mat_elems);              // 64 KB
  unsigned short* Pt = (unsigned short*)(lbuf + (size_t)NB * NTOK);  // 134.2 MB

  hipMemsetAsync(lbuf, 0, (size_t)NB * NTOK * sizeof(float), stream);

  dim3 g1(NTOK / 64, DDIM / 64, NB);
  qkv_proj<<<g1, 256, 0, stream>>>(x, Wq, Wk, Wv, Qt, Kf, Vt);

  dim3 g2(NTOK / 32, 2, NB);
  attn_lsum_p<<<g2, 256, 0, stream>>>(Qt, Kf, Pt, lbuf);

  dim3 g3(NTOK / 64, 2, NB);
  attn_pv<<<g3, 256, 0, stream>>>(Pt, Vt, lbuf, out);

  dim3 g4(128, NB);
  colsum_k<<<g4, 256, 0, stream>>>(Pt, lbuf, scores_out);
}

// Round 7
// 357.099 us; speedup vs baseline: 1.3460x; 1.3460x over previous
//
#include <hip/hip_runtime.h>

// B=4, C=512, H=W=64 -> N=4096 tokens, KEY_DIM=VALUE_DIM=512.
// Pipeline (all matmuls on v_mfma_f32_16x16x32_bf16, fp32 accum):
//   K1 qkv_proj   : Qt (B,N,D) bf16 token-major; K in B-FRAGMENT-TILE layout
//                   Kf[b][kblk(256)][dc(16)][lane(64)][8]; V in A-frag-tile Vt.
//   K2 attn_lsum_p: block = 128 q x 1024 keys (grid 32x4xB, 2 blk/CU).
//                   Wave pins 32 q (2 A-tiles, 128 VGPRs). K staged 64 keys/iter
//                   into 64KB LDS via flat contiguous copy (Kf layout = frag
//                   order); each LDS B-frag read feeds 2 MFMAs (reuse=2, halves
//                   R5's LDS traffic; staging kills R6's 2GB L3 stream).
//                   Pexp scatter-stored to Pt (K3 B-frag layout); l_j via atomics.
//   K3 attn_pv    : O = V.Pexp^T; frag loads 1KB-coalesced; no LDS/barriers.
//   K4 colsum_k   : scores[i] = sum_q Pexp[q,i]/l[q] streaming reduce.
// No max-subtraction in softmax: logits ~ N(0,1), exp() can't overflow.
// ws: Qt/Kf/Vt 50.3 MB + l 64 KB + Pexp 134.2 MB = 184.7 MB.

typedef short bf16x8 __attribute__((ext_vector_type(8)));
typedef float f32x4 __attribute__((ext_vector_type(4)));

#define NTOK 4096
#define DDIM 512
#define NB   4

__device__ __forceinline__ unsigned short f32_bf16(float f) {
  union { float f; unsigned u; } v; v.f = f;
  unsigned r = v.u + 0x7FFFu + ((v.u >> 16) & 1u);  // RNE
  return (unsigned short)(r >> 16);
}

__device__ __forceinline__ float bf16_f32(short s) {
  union { unsigned u; float f; } v;
  v.u = ((unsigned)(unsigned short)s) << 16;
  return v.f;
}

// ---------------------------------------------------------------------------
// K1: QKV projection.  Q[n,d] = sum_c x[c,n] * Wq[d,c]  (x is (C,N) per batch)
// ---------------------------------------------------------------------------
__global__ __launch_bounds__(256, 4) void qkv_proj(
    const float* __restrict__ x,
    const float* __restrict__ Wq,
    const float* __restrict__ Wk,
    const float* __restrict__ Wv,
    unsigned short* __restrict__ Qt,
    unsigned short* __restrict__ Kf,
    unsigned short* __restrict__ Vt)
{
  const int nt0 = blockIdx.x * 64;   // token tile
  const int d0  = blockIdx.y * 64;   // feature tile
  const int b   = blockIdx.z;
  const int tid = threadIdx.x;
  const int wave = tid >> 6;
  const int lane = tid & 63;
  const int l15  = lane & 15;
  const int quad = lane >> 4;

  __shared__ __align__(16) unsigned short Xt[64 * 40];     // [token][c]
  __shared__ __align__(16) unsigned short Wl[3][64 * 40];  // [q/k/v][d][c]

  f32x4 aq[4], ak[4], av[4];
#pragma unroll
  for (int i = 0; i < 4; ++i) {
    aq[i] = (f32x4){0.f,0.f,0.f,0.f};
    ak[i] = (f32x4){0.f,0.f,0.f,0.f};
    av[i] = (f32x4){0.f,0.f,0.f,0.f};
  }

  const float* xb = x + (size_t)b * DDIM * NTOK + nt0;
  const int xn  = tid & 63;
  const int xc8 = tid >> 6;
  const int wc8 = tid & 3;
  const int wdd = tid >> 2;

  for (int cc = 0; cc < DDIM; cc += 32) {
    __syncthreads();
    {
      bf16x8 t;
#pragma unroll
      for (int j = 0; j < 8; ++j)
        t[j] = (short)f32_bf16(xb[(size_t)(cc + xc8 * 8 + j) * NTOK + xn]);
      *(bf16x8*)(&Xt[xn * 40 + xc8 * 8]) = t;
    }
    {
      const float* wsrc[3] = {Wq, Wk, Wv};
#pragma unroll
      for (int m = 0; m < 3; ++m) {
        const float* src = wsrc[m] + (size_t)(d0 + wdd) * DDIM + cc + wc8 * 8;
        bf16x8 t;
#pragma unroll
        for (int j = 0; j < 8; ++j) t[j] = (short)f32_bf16(src[j]);
        *(bf16x8*)(&Wl[m][wdd * 40 + wc8 * 8]) = t;
      }
    }
    __syncthreads();

    bf16x8 xa  = *(const bf16x8*)(&Xt[(wave * 16 + l15) * 40 + quad * 8]);
    bf16x8 wva = *(const bf16x8*)(&Wl[2][(wave * 16 + l15) * 40 + quad * 8]);
#pragma unroll
    for (int nt = 0; nt < 4; ++nt) {
      bf16x8 wqf = *(const bf16x8*)(&Wl[0][(nt * 16 + l15) * 40 + quad * 8]);
      bf16x8 wkf = *(const bf16x8*)(&Wl[1][(nt * 16 + l15) * 40 + quad * 8]);
      bf16x8 xbf = *(const bf16x8*)(&Xt[(nt * 16 + l15) * 40 + quad * 8]);
      aq[nt] = __builtin_amdgcn_mfma_f32_16x16x32_bf16(xa,  wqf, aq[nt], 0, 0, 0);
      ak[nt] = __builtin_amdgcn_mfma_f32_16x16x32_bf16(xa,  wkf, ak[nt], 0, 0, 0);
      av[nt] = __builtin_amdgcn_mfma_f32_16x16x32_bf16(wva, xbf, av[nt], 0, 0, 0);
    }
  }

#pragma unroll
  for (int nt = 0; nt < 4; ++nt) {
#pragma unroll
    for (int r = 0; r < 4; ++r) {
      const int tokq = nt0 + wave * 16 + quad * 4 + r;
      const int dq   = d0 + nt * 16 + l15;
      Qt[((size_t)b * NTOK + tokq) * DDIM + dq] = f32_bf16(aq[nt][r]);
      // K fragment-tile store (B-operand of 16x16x32): key=tokq, d=dq
      {
        const int kblk  = (nt0 >> 4) + wave;
        const int dc    = (d0 >> 5) + (nt >> 1);
        const int laneK = ((nt & 1) * 2 + (l15 >> 3)) * 16 + quad * 4 + r;
        Kf[((size_t)(b * 256 + kblk) * 16 + dc) * 512 + laneK * 8 + (l15 & 7)] =
            f32_bf16(ak[nt][r]);
      }
      // V fragment-tile store: d = d0+wave*16+quad*4+r, i = nt0+nt*16+l15
      const int dblk  = (d0 >> 4) + wave;
      const int ic    = (nt0 >> 5) + (nt >> 1);
      const int laneV = ((nt & 1) * 2 + (l15 >> 3)) * 16 + quad * 4 + r;
      Vt[(size_t)b * DDIM * NTOK +
         ((size_t)(dblk * 128 + ic) * 64 + laneV) * 8 + (l15 & 7)] =
          f32_bf16(av[nt][r]);
    }
  }
}

// ---------------------------------------------------------------------------
#define SCALE 0.044194173824159216f  // 1/sqrt(512)

// ---------------------------------------------------------------------------
// K2: QK^T -> Pexp + row-sum atomics.  Grid (32 qb(128q), 4 kp(1024k), NB).
// Wave owns 32 q (Q frags pinned in regs).  Per kc: stage 64 keys (64KB flat
// copy into LDS), then 4 kt x 16 dc x 2 qt = 128 MFMAs; each B-frag LDS read
// feeds 2 MFMAs.  32 barriers/block, 2 blocks/CU.
// ---------------------------------------------------------------------------
__global__ __launch_bounds__(256, 2) void attn_lsum_p(
    const unsigned short* __restrict__ Qt,
    const unsigned short* __restrict__ Kf,
    unsigned short* __restrict__ Pt,
    float* __restrict__ lsum_g)
{
  const int qb = blockIdx.x;   // 128-q block
  const int kp = blockIdx.y;   // 1024-key part
  const int b  = blockIdx.z;
  const int tid  = threadIdx.x;
  const int wave = tid >> 6;
  const int lane = tid & 63;
  const int l15  = lane & 15;
  const int quad = lane >> 4;
  const int q0   = qb * 128 + wave * 32;  // wave's 32 q

  __shared__ __align__(16) unsigned short Klds[64 * 512];  // 64 KB: 64 frags x 1KB

  // Q A-frags pinned: qf[qt][dc], 2x16x4 VGPRs = 128
  bf16x8 qf[2][16];
#pragma unroll
  for (int qt = 0; qt < 2; ++qt) {
    const unsigned short* qp =
        Qt + ((size_t)b * NTOK + q0 + qt * 16 + l15) * DDIM + quad * 8;
#pragma unroll
    for (int dc = 0; dc < 16; ++dc) qf[qt][dc] = *(const bf16x8*)(qp + dc * 32);
  }

  // P region: 64-q granularity
  unsigned short* Pq = Pt + (size_t)b * NTOK * NTOK +
                       (size_t)(qb * 2 + (wave >> 1)) * 262144;
  const int ntb = (wave & 1) * 2;  // nt base within region

  float ls[2][4] = {{0.f,0.f,0.f,0.f},{0.f,0.f,0.f,0.f}};

  for (int kc = 0; kc < 16; ++kc) {
    const int kblk0 = kp * 64 + kc * 4;  // 4 key-blocks = 64 keys
    __syncthreads();
    {  // stage 64 KB: Kf region is contiguous in frag order -> flat copy
      const unsigned short* src = Kf + ((size_t)(b * 256 + kblk0) * 16) * 512;
#pragma unroll
      for (int it = 0; it < 16; ++it) {
        const int idx = (tid + it * 256) * 8;
        *(bf16x8*)(&Klds[idx]) = *(const bf16x8*)(src + idx);
      }
    }
    __syncthreads();

#pragma unroll
    for (int kt = 0; kt < 4; ++kt) {
      const int kabs = kblk0 + kt;
      f32x4 s0 = (f32x4){0.f,0.f,0.f,0.f};
      f32x4 s1 = (f32x4){0.f,0.f,0.f,0.f};
#pragma unroll
      for (int dc = 0; dc < 16; ++dc) {
        const bf16x8 kbf = *(const bf16x8*)(&Klds[(kt * 16 + dc) * 512 + lane * 8]);
        s0 = __builtin_amdgcn_mfma_f32_16x16x32_bf16(qf[0][dc], kbf, s0, 0, 0, 0);
        s1 = __builtin_amdgcn_mfma_f32_16x16x32_bf16(qf[1][dc], kbf, s1, 0, 0, 0);
      }
      // epilogue: key = kabs*16 + l15, q = q0 + qt*16 + quad*4 + r
      const int ic    = kabs >> 1;
      const int lt_hi = ((kabs & 1) * 2 + (l15 >> 3)) * 16;
      const int jj    = l15 & 7;
#pragma unroll
      for (int r = 0; r < 4; ++r) {
        const float e0 = __expf(s0[r] * SCALE);
        const float e1 = __expf(s1[r] * SCALE);
        ls[0][r] += e0;
        ls[1][r] += e1;
        Pq[((size_t)(ic * 4 + ntb) * 64 + lt_hi + quad * 4 + r) * 8 + jj] =
            f32_bf16(e0);
        Pq[((size_t)(ic * 4 + ntb + 1) * 64 + lt_hi + quad * 4 + r) * 8 + jj] =
            f32_bf16(e1);
      }
    }
  }

  // reduce over the 16 key-columns (l15) and accumulate l_j
#pragma unroll
  for (int qt = 0; qt < 2; ++qt)
#pragma unroll
    for (int r = 0; r < 4; ++r) {
      float v = ls[qt][r];
      v += __shfl_xor(v, 1);
      v += __shfl_xor(v, 2);
      v += __shfl_xor(v, 4);
      v += __shfl_xor(v, 8);
      if (l15 == 0)
        unsafeAtomicAdd(&lsum_g[(size_t)b * NTOK + q0 + qt * 16 + quad * 4 + r], v);
    }
}

// ---------------------------------------------------------------------------
// K3: O = V.Pexp^T.  Grid (64 q0b, 2 dpart, NB) = 512 WGs (2/CU, 8 waves).
// Wave owns 64 d x 64 q.  Per ic: 8 coalesced 1-KB loads + 16 MFMA.
// No LDS, no barriers, no atomics; plain coalesced epilogue stores.
// ---------------------------------------------------------------------------
__global__ __launch_bounds__(256, 2) void attn_pv(
    const unsigned short* __restrict__ Pt,
    const unsigned short* __restrict__ Vt,
    const float* __restrict__ lsum_g,
    float* __restrict__ out)
{
  const int q0b   = blockIdx.x;
  const int dpart = blockIdx.y;
  const int b     = blockIdx.z;
  const int tid  = threadIdx.x;
  const int wave = tid >> 6;
  const int lane = tid & 63;
  const int l15  = lane & 15;
  const int quad = lane >> 4;

  const int dblk0 = dpart * 16 + wave * 4;  // base 16-d tile index
  const unsigned short* Pq =
      Pt + (size_t)b * NTOK * NTOK + (size_t)q0b * 262144 + lane * 8;
  const unsigned short* Vb =
      Vt + (size_t)b * DDIM * NTOK + lane * 8;

  float rlv[4];
#pragma unroll
  for (int nt = 0; nt < 4; ++nt)
    rlv[nt] = 1.0f / lsum_g[(size_t)b * NTOK + q0b * 64 + nt * 16 + l15];

  f32x4 o[4][4];
#pragma unroll
  for (int i = 0; i < 4; ++i)
#pragma unroll
    for (int j = 0; j < 4; ++j) o[i][j] = (f32x4){0.f,0.f,0.f,0.f};

  bf16x8 pc[4], vc[4], pn[4], vn[4];
#pragma unroll
  for (int nt = 0; nt < 4; ++nt)
    pc[nt] = *(const bf16x8*)(Pq + (size_t)nt * 512);
#pragma unroll
  for (int mt = 0; mt < 4; ++mt)
    vc[mt] = *(const bf16x8*)(Vb + (size_t)(dblk0 + mt) * 65536);

#pragma unroll 2
  for (int ic = 0; ic < 127; ++ic) {
    // prefetch next chunk (fully coalesced 1-KB loads)
#pragma unroll
    for (int nt = 0; nt < 4; ++nt)
      pn[nt] = *(const bf16x8*)(Pq + (size_t)(ic + 1) * 2048 + (size_t)nt * 512);
#pragma unroll
    for (int mt = 0; mt < 4; ++mt)
      vn[mt] = *(const bf16x8*)(Vb + (size_t)(dblk0 + mt) * 65536 + (size_t)(ic + 1) * 512);
#pragma unroll
    for (int mt = 0; mt < 4; ++mt)
#pragma unroll
      for (int nt = 0; nt < 4; ++nt)
        o[mt][nt] = __builtin_amdgcn_mfma_f32_16x16x32_bf16(vc[mt], pc[nt], o[mt][nt], 0, 0, 0);
#pragma unroll
    for (int nt = 0; nt < 4; ++nt) pc[nt] = pn[nt];
#pragma unroll
    for (int mt = 0; mt < 4; ++mt) vc[mt] = vn[mt];
  }
#pragma unroll
  for (int mt = 0; mt < 4; ++mt)
#pragma unroll
    for (int nt = 0; nt < 4; ++nt)
      o[mt][nt] = __builtin_amdgcn_mfma_f32_16x16x32_bf16(vc[mt], pc[nt], o[mt][nt], 0, 0, 0);

  // epilogue: plain stores, 1/l folded in (per output column q).
  float* ob = out + ((size_t)b * DDIM + dpart * 256 + wave * 64) * NTOK + q0b * 64;
#pragma unroll
  for (int mt = 0; mt < 4; ++mt)
#pragma unroll
    for (int nt = 0; nt < 4; ++nt)
#pragma unroll
      for (int r = 0; r < 4; ++r)
        ob[(size_t)(mt * 16 + quad * 4 + r) * NTOK + nt * 16 + l15] =
            o[mt][nt][r] * rlv[nt];
}

// ---------------------------------------------------------------------------
// K4: scores[b][i] = sum_q Pexp[b][q][i] / l[b][q].  Tile-layout streaming.
// Grid (128 ic, NB); block exclusively owns i in [ic*32, +32) -> plain stores.
// ---------------------------------------------------------------------------
__global__ __launch_bounds__(256, 4) void colsum_k(
    const unsigned short* __restrict__ Pt,
    const float* __restrict__ lsum_g,
    float* __restrict__ scores_out)
{
  const int ic = blockIdx.x;
  const int b  = blockIdx.y;
  const int tid = threadIdx.x;
  const int wave = tid >> 6;
  const int lane = tid & 63;
  const int l15  = lane & 15;
  const int quad = lane >> 4;

  __shared__ float red[4][32];

  const unsigned short* Pb = Pt + (size_t)b * NTOK * NTOK + (size_t)ic * 2048 + lane * 8;
  const float* lb = lsum_g + (size_t)b * NTOK;

  float acc[8];
#pragma unroll
  for (int j = 0; j < 8; ++j) acc[j] = 0.f;

  for (int q0b = wave; q0b < 64; q0b += 4) {
    const unsigned short* src = Pb + (size_t)q0b * 262144;
#pragma unroll
    for (int nt = 0; nt < 4; ++nt) {
      const bf16x8 p = *(const bf16x8*)(src + (size_t)nt * 512);
      const float rl = 1.0f / lb[q0b * 64 + nt * 16 + l15];
#pragma unroll
      for (int j = 0; j < 8; ++j) acc[j] = fmaf(bf16_f32(p[j]), rl, acc[j]);
    }
  }
  // reduce over the 16 q-residues (l15) within the wave
#pragma unroll
  for (int j = 0; j < 8; ++j) {
    float v = acc[j];
    v += __shfl_xor(v, 1);
    v += __shfl_xor(v, 2);
    v += __shfl_xor(v, 4);
    v += __shfl_xor(v, 8);
    acc[j] = v;
  }
  if (l15 == 0) {
#pragma unroll
    for (int j = 0; j < 8; ++j) red[wave][quad * 8 + j] = acc[j];
  }
  __syncthreads();
  if (tid < 32)
    scores_out[(size_t)b * NTOK + ic * 32 + tid] =
        red[0][tid] + red[1][tid] + red[2][tid] + red[3][tid];
}

// ---------------------------------------------------------------------------
extern "C" void kernel_launch(void* const* d_in, const int* in_sizes, int n_in,
                              void* d_out, int out_size, void* d_ws, size_t ws_size,
                              hipStream_t stream) {
  const float* x  = (const float*)d_in[0];
  const float* Wk = (const float*)d_in[1];  // dict order: x, Wk, Wq, Wv
  const float* Wq = (const float*)d_in[2];
  const float* Wv = (const float*)d_in[3];

  float* out = (float*)d_out;
  float* scores_out = out + (size_t)NB * DDIM * NTOK;  // tail of d_out

  const size_t mat_elems = (size_t)NB * NTOK * DDIM;   // 8388608
  unsigned short* Qt = (unsigned short*)d_ws;
  unsigned short* Kf = Qt + mat_elems;
  unsigned short* Vt = Kf + mat_elems;
  float* lbuf = (float*)(Vt + mat_elems);              // 64 KB
  unsigned short* Pt = (unsigned short*)(lbuf + (size_t)NB * NTOK);  // 134.2 MB

  hipMemsetAsync(lbuf, 0, (size_t)NB * NTOK * sizeof(float), stream);

  dim3 g1(NTOK / 64, DDIM / 64, NB);
  qkv_proj<<<g1, 256, 0, stream>>>(x, Wq, Wk, Wv, Qt, Kf, Vt);

  dim3 g2(NTOK / 128, 4, NB);
  attn_lsum_p<<<g2, 256, 0, stream>>>(Qt, Kf, Pt, lbuf);

  dim3 g3(NTOK / 64, 2, NB);
  attn_pv<<<g3, 256, 0, stream>>>(Pt, Vt, lbuf, out);

  dim3 g4(128, NB);
  colsum_k<<<g4, 256, 0, stream>>>(Pt, lbuf, scores_out);
}